// Round 18
// baseline (201.503 us; speedup 1.0000x reference)
//
#include <hip/hip_runtime.h>
#include <hip/hip_bf16.h>
#include <math.h>

// SPDNet collapsed: ReEig layers are no-ops (spectrum in [0.1, ~4.3] by
// Rayleigh interlacing through orthonormal-column BiMaps), so
//   X3 = (w1 w2 w3)^T X (w1 w2 w3);  out = vec(logm(X3)) @ fc
// logm via degree-24 Chebyshev matrix-Clenshaw on B=(X3-mI)/h, [0.0995,4.8].
// R18: barrier-free, LDS-free X-stream (k_ystrip). Evidence: all barrier-
//   structured bimaps pin at ~2 TB/s; harness fills hit 7 TB/s = many
//   free-running waves, no barriers/LDS. One WAVE per 16-row strip of Y:
//   A-frag rows map to 16 X rows (lane&15), per-lane 8 consecutive fp32
//   per k-slice; W B-frags from L2-hot global with explicit 2-deep
//   in-order-safe pipeline (issue [W_k X_k] pairs; use X_k then W_k two
//   iters later; issue-after-use into (ks&1) slot; full unroll -> static
//   indices). 1792 blocks x 4 waves, launch_bounds(256,3). Y -> global Yt
//   h/l (R15-verified mapping); X3 via verified k_bimap2; idle wave s==25
//   zeroes Yt pad cols. k_logcheb (DEG24) / k_mm / k_wprep unchanged.
// ws layout (floats): T1 @0, X3 @40000, Wth @705600 (ushort[64*448]),
//   Wtl @719936; YtH @800000 (ushort[256*64*416]), YtL @4300000. ~31 MB.

#define CM 2.44975f
#define CH 2.35025f
#define CM_D 2.44975
#define CH_D 2.35025
#define DEG 24
#define PI_D 3.14159265358979323846
#define WKS 448  // global Wth/Wtl k stride
#define YGS 416  // global Yt row stride (ushorts)

typedef __attribute__((ext_vector_type(8))) short short8;
typedef __attribute__((ext_vector_type(4))) float f32x4;

struct ChebC { float c[32]; };

__device__ __forceinline__ ushort bfrne(float x) {
    return __builtin_bit_cast(unsigned short, __float2bfloat16(x));
}
__device__ __forceinline__ float bff(ushort h) {
    return __uint_as_float(((unsigned)h) << 16);
}

__global__ void k_mm(const float* __restrict__ A, const float* __restrict__ B,
                     float* __restrict__ C, int M, int K, int N) {
    int e = blockIdx.x * blockDim.x + threadIdx.x;
    if (e >= M * N) return;
    int r = e / N, c = e % N;
    float acc = 0.f;
    for (int k = 0; k < K; ++k) acc = fmaf(A[r * K + k], B[k * N + c], acc);
    C[e] = acc;
}

// Fused: W = T1 @ w3 (400x100 @ 100x50), transposed + bf16x2 split.
// Wth/Wtl[64][448] c-major, zeros outside [50][400].
__global__ void k_wprep(const float* __restrict__ T1, const float* __restrict__ w3,
                        ushort* __restrict__ Wth, ushort* __restrict__ Wtl) {
    int e = blockIdx.x * blockDim.x + threadIdx.x;
    if (e >= 64 * WKS) return;
    int c = e / WKS, k = e % WKS;
    float v = 0.f;
    if (c < 50 && k < 400)
        for (int j = 0; j < 100; ++j) v = fmaf(T1[k * 100 + j], w3[j * 50 + c], v);
    const ushort h = bfrne(v);
    Wth[e] = h;
    Wtl[e] = bfrne(v - bff(h));
}

// Barrier-free, LDS-free Y = X@W. One wave per 16-row strip (25 strips/batch,
// 7 blocks x 4 waves each; 3 idle waves, one of which zeroes Yt pad cols).
// Per wave: 13 k-slices; A-frag = per-lane 8 consecutive fp32 of X row
// (s*16 + lane&15), cvt'd to bf16 h/l; B-frags (4 n-tiles x h/l) from
// L2-hot global Wth/Wtl. Explicit 2-deep pipeline: slot ks&1 holds W/X for
// ks; refill issued AFTER its MFMAs (in-order vmcnt-safe: use X_k waits
// only loads older than X_k; W_k is older still). ~20 loads in flight/wave,
// 12 waves/CU, zero barriers -> fill-kernel streaming regime.
__global__ __launch_bounds__(256, 3) void k_ystrip(const float* __restrict__ X,
                                                   const ushort* __restrict__ Wth,
                                                   const ushort* __restrict__ Wtl,
                                                   ushort* __restrict__ YtH,
                                                   ushort* __restrict__ YtL) {
    const int tid = threadIdx.x;
    const int wv = tid >> 6, l = tid & 63;
    const int lr = l & 15, lg = l >> 4;
    const int blk = blockIdx.x;
    const int b = blk / 7, sb = blk % 7;
    const int s = sb * 4 + wv;           // strip 0..27
    ushort* __restrict__ dh0 = YtH + (size_t)b * 64 * YGS;
    ushort* __restrict__ dl0 = YtL + (size_t)b * 64 * YGS;

    if (s >= 25) {
        if (s == 25) {  // zero Yt pad cols 400..415 (k_bimap2 reads k<=415)
            #pragma unroll
            for (int q = 0; q < 4; ++q) {
                *(ushort4*)(dh0 + (size_t)l * YGS + 400 + 4 * q) = make_ushort4(0, 0, 0, 0);
                *(ushort4*)(dl0 + (size_t)l * YGS + 400 + 4 * q) = make_ushort4(0, 0, 0, 0);
            }
        }
        return;
    }

    const float* __restrict__ xrow =
        X + (size_t)b * 160000 + (size_t)(s * 16 + lr) * 400 + lg * 8;

    f32x4 acc[4];
    #pragma unroll
    for (int n = 0; n < 4; ++n) acc[n] = (f32x4){0.f, 0.f, 0.f, 0.f};

    short8 Wh2[2][4], Wl2[2][4];
    float4 xa[2], xb[2];

    // prologue: issue [W0 X0][W1 X1]
    #pragma unroll
    for (int k = 0; k < 2; ++k) {
        #pragma unroll
        for (int n = 0; n < 4; ++n) {
            Wh2[k][n] = *(const short8*)&Wth[(n * 16 + lr) * WKS + k * 32 + lg * 8];
            Wl2[k][n] = *(const short8*)&Wtl[(n * 16 + lr) * WKS + k * 32 + lg * 8];
        }
        xa[k] = *(const float4*)(xrow + k * 32);
        xb[k] = *(const float4*)(xrow + k * 32 + 4);
    }

    #pragma unroll
    for (int ks = 0; ks < 13; ++ks) {
        const int cur = ks & 1;  // constant after unroll (static indexing)
        // cvt X_k -> A-frags (fine-grained vmcnt waits only X_k and older)
        const float fv[8] = {xa[cur].x, xa[cur].y, xa[cur].z, xa[cur].w,
                             xb[cur].x, xb[cur].y, xb[cur].z, xb[cur].w};
        short8 Ah, Al;
        #pragma unroll
        for (int i = 0; i < 8; ++i) {
            const ushort h = bfrne(fv[i]);
            Ah[i] = (short)h;
            Al[i] = (short)bfrne(fv[i] - bff(h));
        }
        // 12 MFMA reading W slot cur (W_k is older than X_k: already waited)
        #pragma unroll
        for (int n = 0; n < 4; ++n) {
            acc[n] = __builtin_amdgcn_mfma_f32_16x16x32_bf16(Ah, Wh2[cur][n], acc[n], 0, 0, 0);
            acc[n] = __builtin_amdgcn_mfma_f32_16x16x32_bf16(Ah, Wl2[cur][n], acc[n], 0, 0, 0);
            acc[n] = __builtin_amdgcn_mfma_f32_16x16x32_bf16(Al, Wh2[cur][n], acc[n], 0, 0, 0);
        }
        // refill slot cur with k+2 (issue-after-use; stays in flight 2 iters)
        if (ks + 2 <= 12) {
            const int kn = ks + 2;
            #pragma unroll
            for (int n = 0; n < 4; ++n) {
                Wh2[cur][n] = *(const short8*)&Wth[(n * 16 + lr) * WKS + kn * 32 + lg * 8];
                Wl2[cur][n] = *(const short8*)&Wtl[(n * 16 + lr) * WKS + kn * 32 + lg * 8];
            }
            xa[cur] = *(const float4*)(xrow + kn * 32);
            xb[cur] = *(const float4*)(xrow + kn * 32 + 4);
        }
    }

    // store Y D-frags -> global Yt (bf16 h/l); c = n*16+lr, i = s*16+lg*4+r
    #pragma unroll
    for (int n = 0; n < 4; ++n) {
        const int c = n * 16 + lr;
        const int i0 = s * 16 + lg * 4;
        ushort h[4], lo[4];
        #pragma unroll
        for (int r = 0; r < 4; ++r) {
            h[r] = bfrne(acc[n][r]);
            lo[r] = bfrne(acc[n][r] - bff(h[r]));
        }
        *(ushort4*)(dh0 + (size_t)c * YGS + i0) = make_ushort4(h[0], h[1], h[2], h[3]);
        *(ushort4*)(dl0 + (size_t)c * YGS + i0) = make_ushort4(lo[0], lo[1], lo[2], lo[3]);
    }
}

// One 512-thread block per batch: X3 = W^T Y. Barrier-free, LDS-free;
// A = Wth/Wtl (c-major, k=i), B = Yt (c'-major, k=i), all L2/L3-resident.
// 16 output tiles (4m x 4n of 16x16), 2 per wave. K = 416 (13 ks).
// (verified R15/R16)
__global__ __launch_bounds__(512) void k_bimap2(const ushort* __restrict__ Wth,
                                                const ushort* __restrict__ Wtl,
                                                const ushort* __restrict__ YtH,
                                                const ushort* __restrict__ YtL,
                                                float* __restrict__ X3) {
    const int tid = threadIdx.x;
    const int w = tid >> 6, l = tid & 63;
    const int lr = l & 15, lg = l >> 4;
    const int b = blockIdx.x;
    const ushort* __restrict__ Yh = YtH + (size_t)b * 64 * YGS;
    const ushort* __restrict__ Yl_ = YtL + (size_t)b * 64 * YGS;
    float* __restrict__ dst = X3 + (size_t)b * 2600;

    #pragma unroll
    for (int s = 0; s < 2; ++s) {
        const int tile = w + 8 * s;       // 0..15
        const int m = tile >> 2, n = tile & 3;
        f32x4 a = (f32x4){0.f, 0.f, 0.f, 0.f};
        for (int ks = 0; ks < 13; ++ks) {
            const int ko = ks * 32 + lg * 8;
            const short8 Ah = *(const short8*)&Wth[(m * 16 + lr) * WKS + ko];
            const short8 Al = *(const short8*)&Wtl[(m * 16 + lr) * WKS + ko];
            const short8 Bh = *(const short8*)&Yh[(size_t)(n * 16 + lr) * YGS + ko];
            const short8 Bl = *(const short8*)&Yl_[(size_t)(n * 16 + lr) * YGS + ko];
            a = __builtin_amdgcn_mfma_f32_16x16x32_bf16(Ah, Bh, a, 0, 0, 0);
            a = __builtin_amdgcn_mfma_f32_16x16x32_bf16(Ah, Bl, a, 0, 0, 0);
            a = __builtin_amdgcn_mfma_f32_16x16x32_bf16(Al, Bh, a, 0, 0, 0);
        }
        const int cc = n * 16 + lr;
        if (cc < 52) {
            #pragma unroll
            for (int r = 0; r < 4; ++r) {
                const int rr2 = m * 16 + lg * 4 + r;
                if (rr2 < 50) dst[rr2 * 52 + cc] = a[r];
            }
        }
    }
}

// One 512-thread (8-wave) block per batch: L = p_DEG(B), MFMA Clenshaw.
// (verified R9-R17; DEG 24)
__global__ __launch_bounds__(512) void k_logcheb(const float* __restrict__ X3,
                                                 const ChebC ccf,
                                                 const float* __restrict__ fc,
                                                 float* __restrict__ out) {
    __shared__ ushort ldsU[16384];  // 2 bufs x 2 lvl x 4096 (32 KB)
    __shared__ float Lf[50 * 56];
    __shared__ float red[512 * 7];
    const int tid = threadIdx.x;
    const int w = tid >> 6, l = tid & 63;
    const int lr = l & 15, lg = l >> 4;
    const int b = blockIdx.x;
    const float* __restrict__ src = X3 + (size_t)b * 2600;

    const int mrow = w >> 1;
    const int npair = (w & 1) * 2;

    short8 Ah[2], Al[2];
    {
        const int arow = mrow * 16 + lr;
        const float ih = 1.f / CH;
        #pragma unroll
        for (int ks = 0; ks < 2; ++ks) {
            float x[8];
            #pragma unroll
            for (int hf = 0; hf < 2; ++hf) {
                const int k0 = ks * 32 + lg * 8 + hf * 4;
                float4 v = make_float4(0.f, 0.f, 0.f, 0.f);
                if (arow < 50 && k0 < 52)
                    v = *(const float4*)(src + arow * 52 + k0);
                x[hf * 4 + 0] = v.x; x[hf * 4 + 1] = v.y;
                x[hf * 4 + 2] = v.z; x[hf * 4 + 3] = v.w;
            }
            short8 sh, sl;
            #pragma unroll
            for (int i = 0; i < 8; ++i) {
                const int k = ks * 32 + lg * 8 + i;
                float xv = (x[i] - ((k == arow) ? CM : 0.f)) * ih;
                if (arow >= 50 || k >= 52) xv = 0.f;
                const ushort h = bfrne(xv);
                sh[i] = (short)h;
                sl[i] = (short)bfrne(xv - bff(h));
            }
            Ah[ks] = sh; Al[ks] = sl;
        }
    }

    for (int e = tid; e < 16384; e += 512) ldsU[e] = 0;
    __syncthreads();
    const float cD = ccf.c[DEG];
    if (tid < 50) {  // u1 = cD * I into buf0 (swizzled)
        const ushort h = bfrne(cD);
        const ushort lo = bfrne(cD - bff(h));
        const int idx = tid * 64 + (tid ^ ((tid & 7) << 3));
        ldsU[idx] = h;
        ldsU[4096 + idx] = lo;
    }
    f32x4 u1r[2], u2r[2];
    #pragma unroll
    for (int t = 0; t < 2; ++t) {
        const int colR = (npair + t) * 16 + lr;
        #pragma unroll
        for (int r = 0; r < 4; ++r) {
            const int rowk = mrow * 16 + lg * 4 + r;
            u1r[t][r] = (rowk == colR && rowk < 50) ? cD : 0.f;
            u2r[t][r] = 0.f;
        }
    }
    __syncthreads();

    int cur = 0;
    for (int it = DEG - 1; it >= 0; --it) {
        const float ck = (it == 0) ? 0.5f * ccf.c[0] : ccf.c[it];
        const float two = (it == 0) ? 1.f : 2.f;
        const ushort* bufc = ldsU + cur * 8192;
        ushort* bufn = ldsU + (cur ^ 1) * 8192;

        f32x4 acc[2] = {(f32x4){0.f, 0.f, 0.f, 0.f}, (f32x4){0.f, 0.f, 0.f, 0.f}};
        short8 uh[2][2], ul[2][2];
        #pragma unroll
        for (int t = 0; t < 2; ++t) {
            const int R = (npair + t) * 16 + lr;
            const int swz = (R & 7) << 3;
            #pragma unroll
            for (int ks = 0; ks < 2; ++ks) {
                const int k0 = (ks * 32 + lg * 8) ^ swz;
                uh[t][ks] = *(const short8*)&bufc[R * 64 + k0];
                ul[t][ks] = *(const short8*)&bufc[4096 + R * 64 + k0];
            }
        }
        #pragma unroll
        for (int t = 0; t < 2; ++t) {
            #pragma unroll
            for (int ks = 0; ks < 2; ++ks) {
                acc[t] = __builtin_amdgcn_mfma_f32_16x16x32_bf16(Ah[ks], uh[t][ks], acc[t], 0, 0, 0);
                acc[t] = __builtin_amdgcn_mfma_f32_16x16x32_bf16(Ah[ks], ul[t][ks], acc[t], 0, 0, 0);
                acc[t] = __builtin_amdgcn_mfma_f32_16x16x32_bf16(Al[ks], uh[t][ks], acc[t], 0, 0, 0);
            }
        }
        #pragma unroll
        for (int t = 0; t < 2; ++t) {
            const int colR = (npair + t) * 16 + lr;
            f32x4 un;
            #pragma unroll
            for (int r = 0; r < 4; ++r) {
                const int rowk = mrow * 16 + lg * 4 + r;
                const float dd = (rowk == colR && rowk < 50) ? ck : 0.f;
                un[r] = two * acc[t][r] - u2r[t][r] + dd;
            }
            u2r[t] = u1r[t];
            u1r[t] = un;
            ushort h[4], lo[4];
            #pragma unroll
            for (int r = 0; r < 4; ++r) {
                h[r] = bfrne(un[r]);
                lo[r] = bfrne(un[r] - bff(h[r]));
            }
            const int swz = (colR & 7) << 3;
            const int k0 = (mrow * 16 + lg * 4) ^ swz;
            *(ushort4*)&bufn[colR * 64 + k0] = make_ushort4(h[0], h[1], h[2], h[3]);
            *(ushort4*)&bufn[4096 + colR * 64 + k0] = make_ushort4(lo[0], lo[1], lo[2], lo[3]);
        }
        __syncthreads();
        cur ^= 1;
    }

    #pragma unroll
    for (int t = 0; t < 2; ++t) {
        const int colR = (npair + t) * 16 + lr;
        if (colR < 50) {
            #pragma unroll
            for (int r = 0; r < 4; ++r) {
                const int rowk = mrow * 16 + lg * 4 + r;
                if (rowk < 50) Lf[rowk * 56 + colR] = u1r[t][r];
            }
        }
    }
    __syncthreads();

    float part[7] = {0, 0, 0, 0, 0, 0, 0};
    for (int e = tid; e < 2500; e += 512) {
        const float lv = Lf[(e / 50) * 56 + (e % 50)];
        #pragma unroll
        for (int n = 0; n < 7; ++n) part[n] = fmaf(lv, fc[e * 7 + n], part[n]);
    }
    #pragma unroll
    for (int n = 0; n < 7; ++n) red[tid * 7 + n] = part[n];
    __syncthreads();
    for (int s = 256; s > 0; s >>= 1) {
        if (tid < s) {
            #pragma unroll
            for (int n = 0; n < 7; ++n) red[tid * 7 + n] += red[(tid + s) * 7 + n];
        }
        __syncthreads();
    }
    if (tid < 7) out[b * 7 + tid] = red[tid];
}

extern "C" void kernel_launch(void* const* d_in, const int* in_sizes, int n_in,
                              void* d_out, int out_size, void* d_ws, size_t ws_size,
                              hipStream_t stream) {
    const float* X  = (const float*)d_in[0];
    const float* w1 = (const float*)d_in[1];
    const float* w2 = (const float*)d_in[2];
    const float* w3 = (const float*)d_in[3];
    const float* fc = (const float*)d_in[4];
    float* out = (float*)d_out;

    float* ws    = (float*)d_ws;
    float* T1    = ws;            // 400*100
    float* X3    = ws + 40000;    // 256*2600
    ushort* Wth  = (ushort*)(ws + 705600);   // 64*448 ushorts
    ushort* Wtl  = (ushort*)(ws + 719936);   // 64*448 ushorts
    ushort* YtH  = (ushort*)(ws + 800000);   // 256*64*416 ushorts (~13.6 MB)
    ushort* YtL  = (ushort*)(ws + 4300000);  // same

    // Chebyshev coefficients of log on [CM-CH, CM+CH]: host fp64 128-pt DCT
    ChebC cc;
    {
        double fv[128];
        for (int j = 0; j < 128; ++j)
            fv[j] = log(CM_D + CH_D * cos(PI_D * (j + 0.5) / 128.0));
        for (int t = 0; t < 32; ++t) {
            if (t <= DEG) {
                double s = 0.0;
                for (int j = 0; j < 128; ++j)
                    s += fv[j] * cos(PI_D * t * (j + 0.5) / 128.0);
                cc.c[t] = (float)(s * (2.0 / 128.0));
            } else cc.c[t] = 0.f;
        }
    }

    k_mm<<<(400 * 100 + 255) / 256, 256, 0, stream>>>(w1, w2, T1, 400, 200, 100);
    k_wprep<<<(64 * WKS + 255) / 256, 256, 0, stream>>>(T1, w3, Wth, Wtl);
    k_ystrip<<<256 * 7, 256, 0, stream>>>(X, Wth, Wtl, YtH, YtL);
    k_bimap2<<<256, 512, 0, stream>>>(Wth, Wtl, YtH, YtL, X3);
    k_logcheb<<<256, 512, 0, stream>>>(X3, cc, fc, out);
}

// Round 19
// 70.936 us; speedup vs baseline: 2.8406x; 2.8406x over previous
//
#include <hip/hip_runtime.h>
#include <hip/hip_bf16.h>
#include <math.h>

// SPDNet collapsed: ReEig layers are no-ops (spectrum in [0.1, ~4.3] by
// Rayleigh interlacing through orthonormal-column BiMaps), so
//   X3 = (w1 w2 w3)^T X (w1 w2 w3);  out = vec(logm(X3)) @ fc
// logm via degree-22 Chebyshev matrix-Clenshaw on B=(X3-mI)/h, [0.0995,4.8].
// R19 = R17 (best verified, 118.1 us) + three cuts:
//   (1) phase-1 W B-frags in REGISTERS (tile-invariant per wave; 26 short8
//       = 104 VGPR loaded once) -> halves per-tile LDS b128 reads. WhL/WlL
//       stay in LDS only for phase-2 A-frags (4 b128/tile/wave).
//   (2) DEG 24->22 (Cheb tail ~3.5e-4, 4x margin; absmax has tracked tail).
//   (3) prep via W = w1@(w2@w3): 10 MFLOP vs 20.
//   R18's barrier-free k_ystrip refuted (155us, 754 GB/s: compiler sank the
//   pipeline at VGPR=48 -> serial latency chain; fill-kernel 7 TB/s was
//   WRITES, not reads -> R17 is already ~75% of per-CU read ceiling).
// ws layout (floats): w23 @0 (10000), X3 @40000, Wth @705600
//   (ushort[64*448]), Wtl @719936. ~2.94 MB.

#define CM 2.44975f
#define CH 2.35025f
#define CM_D 2.44975
#define CH_D 2.35025
#define DEG 22
#define PI_D 3.14159265358979323846
#define XHS 424  // X LDS h/l row stride (ushorts); 212 dw %32=20 -> 2-way (free)
#define WLS 424  // W LDS row stride (ushorts)
#define YS 40    // Yt LDS row stride (ushorts)
#define WKS 448  // global Wth/Wtl k stride

typedef __attribute__((ext_vector_type(8))) short short8;
typedef __attribute__((ext_vector_type(4))) float f32x4;

struct ChebC { float c[32]; };

__device__ __forceinline__ ushort bfrne(float x) {
    return __builtin_bit_cast(unsigned short, __float2bfloat16(x));
}
__device__ __forceinline__ float bff(ushort h) {
    return __uint_as_float(((unsigned)h) << 16);
}
// Barrier that does NOT drain vmcnt (pf loads stay in flight).
__device__ __forceinline__ void bar_lds() {
    asm volatile("s_waitcnt lgkmcnt(0)\n\ts_barrier" ::: "memory");
}

// w23 = w2 @ w3 (200x100 @ 100x50)
__global__ void k_mm23(const float* __restrict__ w2, const float* __restrict__ w3,
                       float* __restrict__ w23) {
    int e = blockIdx.x * blockDim.x + threadIdx.x;
    if (e >= 200 * 50) return;
    int r = e / 50, c = e % 50;
    float acc = 0.f;
    for (int k = 0; k < 100; ++k) acc = fmaf(w2[r * 100 + k], w3[k * 50 + c], acc);
    w23[e] = acc;
}

// Fused: W = w1 @ w23 (400x200 @ 200x50), transposed + bf16x2 split.
// Wth/Wtl[64][448] c-major, zeros outside [50][400].
__global__ void k_wprep(const float* __restrict__ w1, const float* __restrict__ w23,
                        ushort* __restrict__ Wth, ushort* __restrict__ Wtl) {
    int e = blockIdx.x * blockDim.x + threadIdx.x;
    if (e >= 64 * WKS) return;
    int c = e / WKS, k = e % WKS;
    float v = 0.f;
    if (c < 50 && k < 400)
        for (int j = 0; j < 200; ++j) v = fmaf(w1[k * 200 + j], w23[j * 50 + c], v);
    const ushort h = bfrne(v);
    Wth[e] = h;
    Wtl[e] = bfrne(v - bff(h));
}

// One 512-thread (8-wave) block per batch. MFMA bf16x2.
// Prologue: phase-1 W B-frags (col c1, 13 ks x h/l) -> REGISTERS;
//   W rows -> LDS h/l (phase-2 A-frags only); X tile0 staged bf16 h/l.
// Per 32-row tile rt (13 tiles):
//   (a) issue 7 contiguous float4 loads of tile rt+1 (only vmem in loop)
//   (b) phase1: Y_tile = Xtile @ W; A = direct b128 LDS reads; B = registers
//   (d) Y D-frags -> Yt[64][40] bf16 h/l;  BAR(lgkm)
//   (f) phase2: X3 += W^T[:, rt*32..+31] @ Y_tile (A from LDS W)
//   (g) drain pf -> cvt once -> XLh/XLl;  BAR(lgkm)
__global__ __launch_bounds__(512, 1) void k_bimap(const float* __restrict__ X,
                                                  const ushort* __restrict__ Wth,
                                                  const ushort* __restrict__ Wtl,
                                                  float* __restrict__ X3) {
    __shared__ ushort XLh[32 * XHS];  // 27136 B
    __shared__ ushort XLl[32 * XHS];  // 27136 B
    __shared__ ushort WhL[52 * WLS];  // 44096 B
    __shared__ ushort WlL[52 * WLS];  // 44096 B
    __shared__ ushort YtH[64 * YS];   // 5120 B
    __shared__ ushort YtL[64 * YS];   // 5120 B   total 152704 B
    const int tid = threadIdx.x;
    const int w = tid >> 6, l = tid & 63;
    const int lr = l & 15, lg = l >> 4;
    const int b = blockIdx.x;
    const float* __restrict__ Xb = X + (size_t)b * 160000;
    const int m1 = w >> 2, n1 = w & 3;
    const int c1 = n1 * 16 + lr;      // Y col / Yt row (0..63)
    const bool v1 = c1 < 52;

    // phase-1 W B-frags into registers (tile-invariant; zeros for c1 >= 52)
    short8 WBh[13], WBl[13];
    #pragma unroll
    for (int ks = 0; ks < 13; ++ks) {
        short8 zh = {0, 0, 0, 0, 0, 0, 0, 0};
        short8 zl = {0, 0, 0, 0, 0, 0, 0, 0};
        if (v1) {
            zh = *(const short8*)&Wth[c1 * WKS + ks * 32 + lg * 8];
            zl = *(const short8*)&Wtl[c1 * WKS + ks * 32 + lg * 8];
        }
        WBh[ks] = zh; WBl[ks] = zl;
    }
    // prologue: W -> LDS (phase-2 A-frags; global zeros at k>=400, rows>=50)
    for (int e = tid; e < 52 * 52; e += 512) {
        const int r = e / 52, k8 = (e % 52) * 8;
        *(short8*)&WhL[r * WLS + k8] = *(const short8*)&Wth[r * WKS + k8];
        *(short8*)&WlL[r * WLS + k8] = *(const short8*)&Wtl[r * WKS + k8];
    }
    // zero X pad cols 400..423 (staging writes cols < 400; MFMA reads to 415)
    for (int e = tid; e < 32 * 24; e += 512) {
        const int rr = e / 24, c = 400 + e % 24;
        XLh[rr * XHS + c] = 0;
        XLl[rr * XHS + c] = 0;
    }
    // stage tile 0 (rows 0..31, fully in-bounds), cvt once
    float4 pf[7];
    #pragma unroll
    for (int j = 0; j < 7; ++j) {
        const int e = tid + 512 * j;
        if (e < 3200) pf[j] = *(const float4*)(Xb + (size_t)e * 4);
    }
    #pragma unroll
    for (int j = 0; j < 7; ++j) {
        const int e = tid + 512 * j;
        if (e < 3200) {
            const int row = e / 100, c4 = (e % 100) * 4;
            const float vv[4] = {pf[j].x, pf[j].y, pf[j].z, pf[j].w};
            ushort h[4], lo[4];
            #pragma unroll
            for (int i = 0; i < 4; ++i) {
                h[i] = bfrne(vv[i]);
                lo[i] = bfrne(vv[i] - bff(h[i]));
            }
            *(ushort4*)&XLh[row * XHS + c4] = make_ushort4(h[0], h[1], h[2], h[3]);
            *(ushort4*)&XLl[row * XHS + c4] = make_ushort4(lo[0], lo[1], lo[2], lo[3]);
        }
    }
    bar_lds();

    f32x4 p2a = (f32x4){0.f, 0.f, 0.f, 0.f};
    f32x4 p2b = (f32x4){0.f, 0.f, 0.f, 0.f};

    for (int rt = 0; rt < 13; ++rt) {
        // (a) issue next-tile loads (private registers; stay in flight)
        if (rt < 12) {
            const size_t gbase = (size_t)(rt + 1) * 12800;
            #pragma unroll
            for (int j = 0; j < 7; ++j) {
                const int e = tid + 512 * j;
                if (e < 3200) {
                    const size_t gf = gbase + (size_t)e * 4;
                    pf[j] = (gf < 160000) ? *(const float4*)(Xb + gf)
                                          : make_float4(0.f, 0.f, 0.f, 0.f);
                }
            }
        }
        // (b) phase1: p1 = Xrows(m1*16+lr) @ Wcols(c1); A from LDS, B regs
        f32x4 p1 = (f32x4){0.f, 0.f, 0.f, 0.f};
        #pragma unroll
        for (int ks = 0; ks < 13; ++ks) {
            const int off = (m1 * 16 + lr) * XHS + ks * 32 + lg * 8;
            const short8 Ah = *(const short8*)&XLh[off];
            const short8 Al = *(const short8*)&XLl[off];
            p1 = __builtin_amdgcn_mfma_f32_16x16x32_bf16(Ah, WBh[ks], p1, 0, 0, 0);
            p1 = __builtin_amdgcn_mfma_f32_16x16x32_bf16(Ah, WBl[ks], p1, 0, 0, 0);
            p1 = __builtin_amdgcn_mfma_f32_16x16x32_bf16(Al, WBh[ks], p1, 0, 0, 0);
        }
        // (d) Yt write (rows c1; i-local m1*16+lg*4)
        {
            const int i0l = m1 * 16 + lg * 4;
            ushort h[4], lo[4];
            #pragma unroll
            for (int r = 0; r < 4; ++r) {
                h[r] = bfrne(p1[r]);
                lo[r] = bfrne(p1[r] - bff(h[r]));
            }
            *(ushort4*)&YtH[c1 * YS + i0l] = make_ushort4(h[0], h[1], h[2], h[3]);
            *(ushort4*)&YtL[c1 * YS + i0l] = make_ushort4(lo[0], lo[1], lo[2], lo[3]);
        }
        bar_lds();  // Yt visible; all phase1 XL readers done
        // (f) phase2: X3 += W^T[:, rt*32 .. +31] @ Y_tile (A from LDS W)
        {
            const int i0 = rt * 32 + lg * 8;
            const short8 Bh2 = *(const short8*)&YtH[c1 * YS + lg * 8];
            const short8 Bl2 = *(const short8*)&YtL[c1 * YS + lg * 8];
            #pragma unroll
            for (int s = 0; s < 2; ++s) {
                const int ra = (m1 + 2 * s) * 16 + lr;
                short8 Ah2 = {0, 0, 0, 0, 0, 0, 0, 0};
                short8 Al2 = {0, 0, 0, 0, 0, 0, 0, 0};
                if (ra < 52) {
                    Ah2 = *(const short8*)&WhL[ra * WLS + i0];
                    Al2 = *(const short8*)&WlL[ra * WLS + i0];
                }
                f32x4& pp = s ? p2b : p2a;
                pp = __builtin_amdgcn_mfma_f32_16x16x32_bf16(Ah2, Bh2, pp, 0, 0, 0);
                pp = __builtin_amdgcn_mfma_f32_16x16x32_bf16(Ah2, Bl2, pp, 0, 0, 0);
                pp = __builtin_amdgcn_mfma_f32_16x16x32_bf16(Al2, Bh2, pp, 0, 0, 0);
            }
        }
        // (g) drain pf -> cvt once -> LDS (vmcnt wait lands here)
        if (rt < 12) {
            #pragma unroll
            for (int j = 0; j < 7; ++j) {
                const int e = tid + 512 * j;
                if (e < 3200) {
                    const int row = e / 100, c4 = (e % 100) * 4;
                    const float vv[4] = {pf[j].x, pf[j].y, pf[j].z, pf[j].w};
                    ushort h[4], lo[4];
                    #pragma unroll
                    for (int i = 0; i < 4; ++i) {
                        h[i] = bfrne(vv[i]);
                        lo[i] = bfrne(vv[i] - bff(h[i]));
                    }
                    *(ushort4*)&XLh[row * XHS + c4] = make_ushort4(h[0], h[1], h[2], h[3]);
                    *(ushort4*)&XLl[row * XHS + c4] = make_ushort4(lo[0], lo[1], lo[2], lo[3]);
                }
            }
        }
        bar_lds();  // staged tile visible; Yt readers done before next write
    }

    float* __restrict__ dst = X3 + (size_t)b * 2600;
    #pragma unroll
    for (int s = 0; s < 2; ++s) {
        const int mm = m1 + 2 * s;
        const f32x4 v = s ? p2b : p2a;
        const int cc = n1 * 16 + lr;
        if (cc < 52) {
            #pragma unroll
            for (int r = 0; r < 4; ++r) {
                const int rr2 = mm * 16 + lg * 4 + r;
                if (rr2 < 50) dst[rr2 * 52 + cc] = v[r];
            }
        }
    }
}

// One 512-thread (8-wave) block per batch: L = p_DEG(B), MFMA Clenshaw.
// (structure verified R9-R17; DEG 22 this round)
__global__ __launch_bounds__(512) void k_logcheb(const float* __restrict__ X3,
                                                 const ChebC ccf,
                                                 const float* __restrict__ fc,
                                                 float* __restrict__ out) {
    __shared__ ushort ldsU[16384];  // 2 bufs x 2 lvl x 4096 (32 KB)
    __shared__ float Lf[50 * 56];
    __shared__ float red[512 * 7];
    const int tid = threadIdx.x;
    const int w = tid >> 6, l = tid & 63;
    const int lr = l & 15, lg = l >> 4;
    const int b = blockIdx.x;
    const float* __restrict__ src = X3 + (size_t)b * 2600;

    const int mrow = w >> 1;
    const int npair = (w & 1) * 2;

    short8 Ah[2], Al[2];
    {
        const int arow = mrow * 16 + lr;
        const float ih = 1.f / CH;
        #pragma unroll
        for (int ks = 0; ks < 2; ++ks) {
            float x[8];
            #pragma unroll
            for (int hf = 0; hf < 2; ++hf) {
                const int k0 = ks * 32 + lg * 8 + hf * 4;
                float4 v = make_float4(0.f, 0.f, 0.f, 0.f);
                if (arow < 50 && k0 < 52)
                    v = *(const float4*)(src + arow * 52 + k0);
                x[hf * 4 + 0] = v.x; x[hf * 4 + 1] = v.y;
                x[hf * 4 + 2] = v.z; x[hf * 4 + 3] = v.w;
            }
            short8 sh, sl;
            #pragma unroll
            for (int i = 0; i < 8; ++i) {
                const int k = ks * 32 + lg * 8 + i;
                float xv = (x[i] - ((k == arow) ? CM : 0.f)) * ih;
                if (arow >= 50 || k >= 52) xv = 0.f;
                const ushort h = bfrne(xv);
                sh[i] = (short)h;
                sl[i] = (short)bfrne(xv - bff(h));
            }
            Ah[ks] = sh; Al[ks] = sl;
        }
    }

    for (int e = tid; e < 16384; e += 512) ldsU[e] = 0;
    __syncthreads();
    const float cD = ccf.c[DEG];
    if (tid < 50) {  // u1 = cD * I into buf0 (swizzled)
        const ushort h = bfrne(cD);
        const ushort lo = bfrne(cD - bff(h));
        const int idx = tid * 64 + (tid ^ ((tid & 7) << 3));
        ldsU[idx] = h;
        ldsU[4096 + idx] = lo;
    }
    f32x4 u1r[2], u2r[2];
    #pragma unroll
    for (int t = 0; t < 2; ++t) {
        const int colR = (npair + t) * 16 + lr;
        #pragma unroll
        for (int r = 0; r < 4; ++r) {
            const int rowk = mrow * 16 + lg * 4 + r;
            u1r[t][r] = (rowk == colR && rowk < 50) ? cD : 0.f;
            u2r[t][r] = 0.f;
        }
    }
    __syncthreads();

    int cur = 0;
    for (int it = DEG - 1; it >= 0; --it) {
        const float ck = (it == 0) ? 0.5f * ccf.c[0] : ccf.c[it];
        const float two = (it == 0) ? 1.f : 2.f;
        const ushort* bufc = ldsU + cur * 8192;
        ushort* bufn = ldsU + (cur ^ 1) * 8192;

        f32x4 acc[2] = {(f32x4){0.f, 0.f, 0.f, 0.f}, (f32x4){0.f, 0.f, 0.f, 0.f}};
        short8 uh[2][2], ul[2][2];
        #pragma unroll
        for (int t = 0; t < 2; ++t) {
            const int R = (npair + t) * 16 + lr;
            const int swz = (R & 7) << 3;
            #pragma unroll
            for (int ks = 0; ks < 2; ++ks) {
                const int k0 = (ks * 32 + lg * 8) ^ swz;
                uh[t][ks] = *(const short8*)&bufc[R * 64 + k0];
                ul[t][ks] = *(const short8*)&bufc[4096 + R * 64 + k0];
            }
        }
        #pragma unroll
        for (int t = 0; t < 2; ++t) {
            #pragma unroll
            for (int ks = 0; ks < 2; ++ks) {
                acc[t] = __builtin_amdgcn_mfma_f32_16x16x32_bf16(Ah[ks], uh[t][ks], acc[t], 0, 0, 0);
                acc[t] = __builtin_amdgcn_mfma_f32_16x16x32_bf16(Ah[ks], ul[t][ks], acc[t], 0, 0, 0);
                acc[t] = __builtin_amdgcn_mfma_f32_16x16x32_bf16(Al[ks], uh[t][ks], acc[t], 0, 0, 0);
            }
        }
        #pragma unroll
        for (int t = 0; t < 2; ++t) {
            const int colR = (npair + t) * 16 + lr;
            f32x4 un;
            #pragma unroll
            for (int r = 0; r < 4; ++r) {
                const int rowk = mrow * 16 + lg * 4 + r;
                const float dd = (rowk == colR && rowk < 50) ? ck : 0.f;
                un[r] = two * acc[t][r] - u2r[t][r] + dd;
            }
            u2r[t] = u1r[t];
            u1r[t] = un;
            ushort h[4], lo[4];
            #pragma unroll
            for (int r = 0; r < 4; ++r) {
                h[r] = bfrne(un[r]);
                lo[r] = bfrne(un[r] - bff(h[r]));
            }
            const int swz = (colR & 7) << 3;
            const int k0 = (mrow * 16 + lg * 4) ^ swz;
            *(ushort4*)&bufn[colR * 64 + k0] = make_ushort4(h[0], h[1], h[2], h[3]);
            *(ushort4*)&bufn[4096 + colR * 64 + k0] = make_ushort4(lo[0], lo[1], lo[2], lo[3]);
        }
        __syncthreads();
        cur ^= 1;
    }

    #pragma unroll
    for (int t = 0; t < 2; ++t) {
        const int colR = (npair + t) * 16 + lr;
        if (colR < 50) {
            #pragma unroll
            for (int r = 0; r < 4; ++r) {
                const int rowk = mrow * 16 + lg * 4 + r;
                if (rowk < 50) Lf[rowk * 56 + colR] = u1r[t][r];
            }
        }
    }
    __syncthreads();

    float part[7] = {0, 0, 0, 0, 0, 0, 0};
    for (int e = tid; e < 2500; e += 512) {
        const float lv = Lf[(e / 50) * 56 + (e % 50)];
        #pragma unroll
        for (int n = 0; n < 7; ++n) part[n] = fmaf(lv, fc[e * 7 + n], part[n]);
    }
    #pragma unroll
    for (int n = 0; n < 7; ++n) red[tid * 7 + n] = part[n];
    __syncthreads();
    for (int s = 256; s > 0; s >>= 1) {
        if (tid < s) {
            #pragma unroll
            for (int n = 0; n < 7; ++n) red[tid * 7 + n] += red[(tid + s) * 7 + n];
        }
        __syncthreads();
    }
    if (tid < 7) out[b * 7 + tid] = red[tid];
}

extern "C" void kernel_launch(void* const* d_in, const int* in_sizes, int n_in,
                              void* d_out, int out_size, void* d_ws, size_t ws_size,
                              hipStream_t stream) {
    const float* X  = (const float*)d_in[0];
    const float* w1 = (const float*)d_in[1];
    const float* w2 = (const float*)d_in[2];
    const float* w3 = (const float*)d_in[3];
    const float* fc = (const float*)d_in[4];
    float* out = (float*)d_out;

    float* ws    = (float*)d_ws;
    float* w23   = ws;            // 200*50
    float* X3    = ws + 40000;    // 256*2600
    ushort* Wth  = (ushort*)(ws + 705600);   // 64*448 ushorts
    ushort* Wtl  = (ushort*)(ws + 719936);   // 64*448 ushorts

    // Chebyshev coefficients of log on [CM-CH, CM+CH]: host fp64 128-pt DCT
    ChebC cc;
    {
        double fv[128];
        for (int j = 0; j < 128; ++j)
            fv[j] = log(CM_D + CH_D * cos(PI_D * (j + 0.5) / 128.0));
        for (int t = 0; t < 32; ++t) {
            if (t <= DEG) {
                double s = 0.0;
                for (int j = 0; j < 128; ++j)
                    s += fv[j] * cos(PI_D * t * (j + 0.5) / 128.0);
                cc.c[t] = (float)(s * (2.0 / 128.0));
            } else cc.c[t] = 0.f;
        }
    }

    k_mm23<<<(200 * 50 + 255) / 256, 256, 0, stream>>>(w2, w3, w23);
    k_wprep<<<(64 * WKS + 255) / 256, 256, 0, stream>>>(w1, w23, Wth, Wtl);
    k_bimap<<<256, 512, 0, stream>>>(X, Wth, Wtl, X3);
    k_logcheb<<<256, 512, 0, stream>>>(X3, cc, fc, out);
}

// Round 20
// 68.420 us; speedup vs baseline: 2.9451x; 1.0368x over previous
//
#include <hip/hip_runtime.h>
#include <hip/hip_bf16.h>
#include <math.h>

// SPDNet collapsed: ReEig layers are no-ops (spectrum in [0.1, ~4.3] by
// Rayleigh interlacing through orthonormal-column BiMaps), so
//   X3 = (w1 w2 w3)^T X (w1 w2 w3);  out = vec(logm(X3)) @ fc
// logm via degree-22 Chebyshev matrix-Clenshaw on B=(X3-mI)/h, [0.0995,4.8].
// R20 = R19 (70.9 us) with k_bimap + k_logcheb FUSED into k_fused:
//   one 512-thread block per batch runs bimap phases then Clenshaw phases
//   over a shared LDS arena; X3 stays on-chip (p2 frags -> X3L[50*52] LDS
//   @60000B, disjoint from logcheb's ldsU/Lf/red regions). Removes one
//   launch gap + the X3 global round-trip. Math path bit-identical to R19
//   (absmax must stay 2.441e-4; deviation = fusion bug).
// Arena (bytes): bimap XLh@0 XLl@27136 WhL@54272 WlL@98368 YtH@142464
//   YtL@147584 (152704 total); logcheb ldsU@0(32768) Lf@32768(11200)
//   red@44032(14336) X3L@60000(10400) — X3L written after final bimap
//   barrier (all bimap buffers dead), never touched by ldsU zeroing.
// ws layout (floats): w23 @0 (10000), Wth @705600 (ushort[64*448]),
//   Wtl @719936. ~2.94 MB.

#define CM 2.44975f
#define CH 2.35025f
#define CM_D 2.44975
#define CH_D 2.35025
#define DEG 22
#define PI_D 3.14159265358979323846
#define XHS 424  // X LDS h/l row stride (ushorts)
#define WLS 424  // W LDS row stride (ushorts)
#define YS 40    // Yt LDS row stride (ushorts)
#define WKS 448  // global Wth/Wtl k stride

typedef __attribute__((ext_vector_type(8))) short short8;
typedef __attribute__((ext_vector_type(4))) float f32x4;

struct ChebC { float c[32]; };

__device__ __forceinline__ ushort bfrne(float x) {
    return __builtin_bit_cast(unsigned short, __float2bfloat16(x));
}
__device__ __forceinline__ float bff(ushort h) {
    return __uint_as_float(((unsigned)h) << 16);
}
// Barrier that does NOT drain vmcnt (pf loads stay in flight).
__device__ __forceinline__ void bar_lds() {
    asm volatile("s_waitcnt lgkmcnt(0)\n\ts_barrier" ::: "memory");
}

// w23 = w2 @ w3 (200x100 @ 100x50)
__global__ void k_mm23(const float* __restrict__ w2, const float* __restrict__ w3,
                       float* __restrict__ w23) {
    int e = blockIdx.x * blockDim.x + threadIdx.x;
    if (e >= 200 * 50) return;
    int r = e / 50, c = e % 50;
    float acc = 0.f;
    for (int k = 0; k < 100; ++k) acc = fmaf(w2[r * 100 + k], w3[k * 50 + c], acc);
    w23[e] = acc;
}

// Fused: W = w1 @ w23 (400x200 @ 200x50), transposed + bf16x2 split.
// Wth/Wtl[64][448] c-major, zeros outside [50][400].
__global__ void k_wprep(const float* __restrict__ w1, const float* __restrict__ w23,
                        ushort* __restrict__ Wth, ushort* __restrict__ Wtl) {
    int e = blockIdx.x * blockDim.x + threadIdx.x;
    if (e >= 64 * WKS) return;
    int c = e / WKS, k = e % WKS;
    float v = 0.f;
    if (c < 50 && k < 400)
        for (int j = 0; j < 200; ++j) v = fmaf(w1[k * 200 + j], w23[j * 50 + c], v);
    const ushort h = bfrne(v);
    Wth[e] = h;
    Wtl[e] = bfrne(v - bff(h));
}

// One 512-thread (8-wave) block per batch: full pipeline
//   X3 = W^T X W  (R19's k_bimap: reg W B-frags, bf16-h/l staged X,
//                  raw lgkm barriers, incremental phase-2)
//   L = p_DEG((X3-mI)/h)  (R9-R19's MFMA Clenshaw)
//   out = vec(L) @ fc
// X3 transits through LDS only.
__global__ __launch_bounds__(512, 1) void k_fused(const float* __restrict__ X,
                                                  const ushort* __restrict__ Wth,
                                                  const ushort* __restrict__ Wtl,
                                                  const ChebC ccf,
                                                  const float* __restrict__ fc,
                                                  float* __restrict__ out) {
    __shared__ __align__(16) char arena[152704];
    ushort* XLh = (ushort*)(arena);            // 27136 B
    ushort* XLl = (ushort*)(arena + 27136);    // 27136 B
    ushort* WhL = (ushort*)(arena + 54272);    // 44096 B
    ushort* WlL = (ushort*)(arena + 98368);    // 44096 B
    ushort* YtH = (ushort*)(arena + 142464);   // 5120 B
    ushort* YtL = (ushort*)(arena + 147584);   // 5120 B
    // logcheb regions (valid after bimap completes):
    ushort* ldsU = (ushort*)(arena);           // 32768 B
    float*  Lf   = (float*)(arena + 32768);    // 11200 B
    float*  red  = (float*)(arena + 44032);    // 14336 B
    float*  X3L  = (float*)(arena + 60000);    // 10400 B (50x52)

    const int tid = threadIdx.x;
    const int w = tid >> 6, l = tid & 63;
    const int lr = l & 15, lg = l >> 4;
    const int b = blockIdx.x;
    const float* __restrict__ Xb = X + (size_t)b * 160000;
    const int m1 = w >> 2, n1 = w & 3;
    const int c1 = n1 * 16 + lr;      // Y col / Yt row (0..63)
    const bool v1 = c1 < 52;

    // ---------------- bimap ----------------
    // phase-1 W B-frags into registers (tile-invariant; zeros for c1 >= 52)
    short8 WBh[13], WBl[13];
    #pragma unroll
    for (int ks = 0; ks < 13; ++ks) {
        short8 zh = {0, 0, 0, 0, 0, 0, 0, 0};
        short8 zl = {0, 0, 0, 0, 0, 0, 0, 0};
        if (v1) {
            zh = *(const short8*)&Wth[c1 * WKS + ks * 32 + lg * 8];
            zl = *(const short8*)&Wtl[c1 * WKS + ks * 32 + lg * 8];
        }
        WBh[ks] = zh; WBl[ks] = zl;
    }
    // W -> LDS (phase-2 A-frags; global zeros at k>=400, rows>=50)
    for (int e = tid; e < 52 * 52; e += 512) {
        const int r = e / 52, k8 = (e % 52) * 8;
        *(short8*)&WhL[r * WLS + k8] = *(const short8*)&Wth[r * WKS + k8];
        *(short8*)&WlL[r * WLS + k8] = *(const short8*)&Wtl[r * WKS + k8];
    }
    // zero X pad cols 400..423
    for (int e = tid; e < 32 * 24; e += 512) {
        const int rr = e / 24, c = 400 + e % 24;
        XLh[rr * XHS + c] = 0;
        XLl[rr * XHS + c] = 0;
    }
    // stage tile 0, cvt once
    float4 pf[7];
    #pragma unroll
    for (int j = 0; j < 7; ++j) {
        const int e = tid + 512 * j;
        if (e < 3200) pf[j] = *(const float4*)(Xb + (size_t)e * 4);
    }
    #pragma unroll
    for (int j = 0; j < 7; ++j) {
        const int e = tid + 512 * j;
        if (e < 3200) {
            const int row = e / 100, c4 = (e % 100) * 4;
            const float vv[4] = {pf[j].x, pf[j].y, pf[j].z, pf[j].w};
            ushort h[4], lo[4];
            #pragma unroll
            for (int i = 0; i < 4; ++i) {
                h[i] = bfrne(vv[i]);
                lo[i] = bfrne(vv[i] - bff(h[i]));
            }
            *(ushort4*)&XLh[row * XHS + c4] = make_ushort4(h[0], h[1], h[2], h[3]);
            *(ushort4*)&XLl[row * XHS + c4] = make_ushort4(lo[0], lo[1], lo[2], lo[3]);
        }
    }
    bar_lds();

    f32x4 p2a = (f32x4){0.f, 0.f, 0.f, 0.f};
    f32x4 p2b = (f32x4){0.f, 0.f, 0.f, 0.f};

    for (int rt = 0; rt < 13; ++rt) {
        // (a) issue next-tile loads
        if (rt < 12) {
            const size_t gbase = (size_t)(rt + 1) * 12800;
            #pragma unroll
            for (int j = 0; j < 7; ++j) {
                const int e = tid + 512 * j;
                if (e < 3200) {
                    const size_t gf = gbase + (size_t)e * 4;
                    pf[j] = (gf < 160000) ? *(const float4*)(Xb + gf)
                                          : make_float4(0.f, 0.f, 0.f, 0.f);
                }
            }
        }
        // (b) phase1: A from LDS, B regs
        f32x4 p1 = (f32x4){0.f, 0.f, 0.f, 0.f};
        #pragma unroll
        for (int ks = 0; ks < 13; ++ks) {
            const int off = (m1 * 16 + lr) * XHS + ks * 32 + lg * 8;
            const short8 Ah = *(const short8*)&XLh[off];
            const short8 Al = *(const short8*)&XLl[off];
            p1 = __builtin_amdgcn_mfma_f32_16x16x32_bf16(Ah, WBh[ks], p1, 0, 0, 0);
            p1 = __builtin_amdgcn_mfma_f32_16x16x32_bf16(Ah, WBl[ks], p1, 0, 0, 0);
            p1 = __builtin_amdgcn_mfma_f32_16x16x32_bf16(Al, WBh[ks], p1, 0, 0, 0);
        }
        // (d) Yt write
        {
            const int i0l = m1 * 16 + lg * 4;
            ushort h[4], lo[4];
            #pragma unroll
            for (int r = 0; r < 4; ++r) {
                h[r] = bfrne(p1[r]);
                lo[r] = bfrne(p1[r] - bff(h[r]));
            }
            *(ushort4*)&YtH[c1 * YS + i0l] = make_ushort4(h[0], h[1], h[2], h[3]);
            *(ushort4*)&YtL[c1 * YS + i0l] = make_ushort4(lo[0], lo[1], lo[2], lo[3]);
        }
        bar_lds();
        // (f) phase2: X3 += W^T[:, rt*32 .. +31] @ Y_tile
        {
            const int i0 = rt * 32 + lg * 8;
            const short8 Bh2 = *(const short8*)&YtH[c1 * YS + lg * 8];
            const short8 Bl2 = *(const short8*)&YtL[c1 * YS + lg * 8];
            #pragma unroll
            for (int s = 0; s < 2; ++s) {
                const int ra = (m1 + 2 * s) * 16 + lr;
                short8 Ah2 = {0, 0, 0, 0, 0, 0, 0, 0};
                short8 Al2 = {0, 0, 0, 0, 0, 0, 0, 0};
                if (ra < 52) {
                    Ah2 = *(const short8*)&WhL[ra * WLS + i0];
                    Al2 = *(const short8*)&WlL[ra * WLS + i0];
                }
                f32x4& pp = s ? p2b : p2a;
                pp = __builtin_amdgcn_mfma_f32_16x16x32_bf16(Ah2, Bh2, pp, 0, 0, 0);
                pp = __builtin_amdgcn_mfma_f32_16x16x32_bf16(Ah2, Bl2, pp, 0, 0, 0);
                pp = __builtin_amdgcn_mfma_f32_16x16x32_bf16(Al2, Bh2, pp, 0, 0, 0);
            }
        }
        // (g) drain pf -> cvt once -> LDS
        if (rt < 12) {
            #pragma unroll
            for (int j = 0; j < 7; ++j) {
                const int e = tid + 512 * j;
                if (e < 3200) {
                    const int row = e / 100, c4 = (e % 100) * 4;
                    const float vv[4] = {pf[j].x, pf[j].y, pf[j].z, pf[j].w};
                    ushort h[4], lo[4];
                    #pragma unroll
                    for (int i = 0; i < 4; ++i) {
                        h[i] = bfrne(vv[i]);
                        lo[i] = bfrne(vv[i] - bff(h[i]));
                    }
                    *(ushort4*)&XLh[row * XHS + c4] = make_ushort4(h[0], h[1], h[2], h[3]);
                    *(ushort4*)&XLl[row * XHS + c4] = make_ushort4(lo[0], lo[1], lo[2], lo[3]);
                }
            }
        }
        bar_lds();  // after last iter: ALL bimap LDS dead
    }

    // X3 -> LDS (X3L disjoint from ldsU/Lf/red; bimap buffers dead)
    #pragma unroll
    for (int s = 0; s < 2; ++s) {
        const int mm = m1 + 2 * s;
        const f32x4 v = s ? p2b : p2a;
        const int cc = n1 * 16 + lr;
        if (cc < 52) {
            #pragma unroll
            for (int r = 0; r < 4; ++r) {
                const int rr2 = mm * 16 + lg * 4 + r;
                if (rr2 < 50) X3L[rr2 * 52 + cc] = v[r];
            }
        }
    }
    __syncthreads();

    // ---------------- logcheb ----------------
    const int mrow = w >> 1;
    const int npair = (w & 1) * 2;

    short8 Ah[2], Al[2];
    {
        const int arow = mrow * 16 + lr;
        const float ih = 1.f / CH;
        #pragma unroll
        for (int ks = 0; ks < 2; ++ks) {
            float x[8];
            #pragma unroll
            for (int hf = 0; hf < 2; ++hf) {
                const int k0 = ks * 32 + lg * 8 + hf * 4;
                float4 v = make_float4(0.f, 0.f, 0.f, 0.f);
                if (arow < 50 && k0 < 52)
                    v = *(const float4*)(X3L + arow * 52 + k0);
                x[hf * 4 + 0] = v.x; x[hf * 4 + 1] = v.y;
                x[hf * 4 + 2] = v.z; x[hf * 4 + 3] = v.w;
            }
            short8 sh, sl;
            #pragma unroll
            for (int i = 0; i < 8; ++i) {
                const int k = ks * 32 + lg * 8 + i;
                float xv = (x[i] - ((k == arow) ? CM : 0.f)) * ih;
                if (arow >= 50 || k >= 52) xv = 0.f;
                const ushort h = bfrne(xv);
                sh[i] = (short)h;
                sl[i] = (short)bfrne(xv - bff(h));
            }
            Ah[ks] = sh; Al[ks] = sl;
        }
    }
    __syncthreads();  // all X3L reads done before ldsU zeroing (disjoint anyway)

    for (int e = tid; e < 16384; e += 512) ldsU[e] = 0;
    __syncthreads();
    const float cD = ccf.c[DEG];
    if (tid < 50) {  // u1 = cD * I into buf0 (swizzled)
        const ushort h = bfrne(cD);
        const ushort lo = bfrne(cD - bff(h));
        const int idx = tid * 64 + (tid ^ ((tid & 7) << 3));
        ldsU[idx] = h;
        ldsU[4096 + idx] = lo;
    }
    f32x4 u1r[2], u2r[2];
    #pragma unroll
    for (int t = 0; t < 2; ++t) {
        const int colR = (npair + t) * 16 + lr;
        #pragma unroll
        for (int r = 0; r < 4; ++r) {
            const int rowk = mrow * 16 + lg * 4 + r;
            u1r[t][r] = (rowk == colR && rowk < 50) ? cD : 0.f;
            u2r[t][r] = 0.f;
        }
    }
    __syncthreads();

    int cur = 0;
    for (int it = DEG - 1; it >= 0; --it) {
        const float ck = (it == 0) ? 0.5f * ccf.c[0] : ccf.c[it];
        const float two = (it == 0) ? 1.f : 2.f;
        const ushort* bufc = ldsU + cur * 8192;
        ushort* bufn = ldsU + (cur ^ 1) * 8192;

        f32x4 acc[2] = {(f32x4){0.f, 0.f, 0.f, 0.f}, (f32x4){0.f, 0.f, 0.f, 0.f}};
        short8 uh[2][2], ul[2][2];
        #pragma unroll
        for (int t = 0; t < 2; ++t) {
            const int R = (npair + t) * 16 + lr;
            const int swz = (R & 7) << 3;
            #pragma unroll
            for (int ks = 0; ks < 2; ++ks) {
                const int k0 = (ks * 32 + lg * 8) ^ swz;
                uh[t][ks] = *(const short8*)&bufc[R * 64 + k0];
                ul[t][ks] = *(const short8*)&bufc[4096 + R * 64 + k0];
            }
        }
        #pragma unroll
        for (int t = 0; t < 2; ++t) {
            #pragma unroll
            for (int ks = 0; ks < 2; ++ks) {
                acc[t] = __builtin_amdgcn_mfma_f32_16x16x32_bf16(Ah[ks], uh[t][ks], acc[t], 0, 0, 0);
                acc[t] = __builtin_amdgcn_mfma_f32_16x16x32_bf16(Ah[ks], ul[t][ks], acc[t], 0, 0, 0);
                acc[t] = __builtin_amdgcn_mfma_f32_16x16x32_bf16(Al[ks], uh[t][ks], acc[t], 0, 0, 0);
            }
        }
        #pragma unroll
        for (int t = 0; t < 2; ++t) {
            const int colR = (npair + t) * 16 + lr;
            f32x4 un;
            #pragma unroll
            for (int r = 0; r < 4; ++r) {
                const int rowk = mrow * 16 + lg * 4 + r;
                const float dd = (rowk == colR && rowk < 50) ? ck : 0.f;
                un[r] = two * acc[t][r] - u2r[t][r] + dd;
            }
            u2r[t] = u1r[t];
            u1r[t] = un;
            ushort h[4], lo[4];
            #pragma unroll
            for (int r = 0; r < 4; ++r) {
                h[r] = bfrne(un[r]);
                lo[r] = bfrne(un[r] - bff(h[r]));
            }
            const int swz = (colR & 7) << 3;
            const int k0 = (mrow * 16 + lg * 4) ^ swz;
            *(ushort4*)&bufn[colR * 64 + k0] = make_ushort4(h[0], h[1], h[2], h[3]);
            *(ushort4*)&bufn[4096 + colR * 64 + k0] = make_ushort4(lo[0], lo[1], lo[2], lo[3]);
        }
        __syncthreads();
        cur ^= 1;
    }

    #pragma unroll
    for (int t = 0; t < 2; ++t) {
        const int colR = (npair + t) * 16 + lr;
        if (colR < 50) {
            #pragma unroll
            for (int r = 0; r < 4; ++r) {
                const int rowk = mrow * 16 + lg * 4 + r;
                if (rowk < 50) Lf[rowk * 56 + colR] = u1r[t][r];
            }
        }
    }
    __syncthreads();

    float part[7] = {0, 0, 0, 0, 0, 0, 0};
    for (int e = tid; e < 2500; e += 512) {
        const float lv = Lf[(e / 50) * 56 + (e % 50)];
        #pragma unroll
        for (int n = 0; n < 7; ++n) part[n] = fmaf(lv, fc[e * 7 + n], part[n]);
    }
    #pragma unroll
    for (int n = 0; n < 7; ++n) red[tid * 7 + n] = part[n];
    __syncthreads();
    for (int s = 256; s > 0; s >>= 1) {
        if (tid < s) {
            #pragma unroll
            for (int n = 0; n < 7; ++n) red[tid * 7 + n] += red[(tid + s) * 7 + n];
        }
        __syncthreads();
    }
    if (tid < 7) out[b * 7 + tid] = red[tid];
}

extern "C" void kernel_launch(void* const* d_in, const int* in_sizes, int n_in,
                              void* d_out, int out_size, void* d_ws, size_t ws_size,
                              hipStream_t stream) {
    const float* X  = (const float*)d_in[0];
    const float* w1 = (const float*)d_in[1];
    const float* w2 = (const float*)d_in[2];
    const float* w3 = (const float*)d_in[3];
    const float* fc = (const float*)d_in[4];
    float* out = (float*)d_out;

    float* ws    = (float*)d_ws;
    float* w23   = ws;            // 200*50
    ushort* Wth  = (ushort*)(ws + 705600);   // 64*448 ushorts
    ushort* Wtl  = (ushort*)(ws + 719936);   // 64*448 ushorts

    // Chebyshev coefficients of log on [CM-CH, CM+CH]: host fp64 128-pt DCT
    ChebC cc;
    {
        double fv[128];
        for (int j = 0; j < 128; ++j)
            fv[j] = log(CM_D + CH_D * cos(PI_D * (j + 0.5) / 128.0));
        for (int t = 0; t < 32; ++t) {
            if (t <= DEG) {
                double s = 0.0;
                for (int j = 0; j < 128; ++j)
                    s += fv[j] * cos(PI_D * t * (j + 0.5) / 128.0);
                cc.c[t] = (float)(s * (2.0 / 128.0));
            } else cc.c[t] = 0.f;
        }
    }

    k_mm23<<<(200 * 50 + 255) / 256, 256, 0, stream>>>(w2, w3, w23);
    k_wprep<<<(64 * WKS + 255) / 256, 256, 0, stream>>>(w1, w23, Wth, Wtl);
    k_fused<<<256, 512, 0, stream>>>(X, Wth, Wtl, cc, fc, out);
}